// Round 8
// baseline (200.968 us; speedup 1.0000x reference)
//
#include <hip/hip_runtime.h>

#define D 128          // D_IN == D_OUT == 128
#define RPB 512        // rows per bucket
#define RPB_SHIFT 9
#define HALF 256       // rows handled per csr_build block
#define BUCKMAX 256
#define TILE 8192      // edges per binning tile
#define SEGCAP 7168    // LDS pair capacity per csr_build block (56 KiB)

typedef short bf16x8 __attribute__((ext_vector_type(8)));
typedef float f32x4 __attribute__((ext_vector_type(4)));

__device__ inline unsigned short f2bf(float f) {  // RNE float->bf16
    unsigned u = __float_as_uint(f);
    unsigned r = u + 0x7FFFu + ((u >> 16) & 1u);
    return (unsigned short)(r >> 16);
}

// ---------------------------------------------------------------------------
// Fused: cast x -> bf16 (grid-stride), then per-bucket edge histogram.
// ---------------------------------------------------------------------------
__global__ __launch_bounds__(256) void cast_x_hist(const float* __restrict__ x,
                                                   unsigned short* __restrict__ xb,
                                                   long long n4,
                                                   const int* __restrict__ rows,
                                                   int* __restrict__ bucketCnt,
                                                   int E, int NBUCK) {
    // phase A: cast
    {
        long long i = (long long)blockIdx.x * 256 + threadIdx.x;
        const long long stride = (long long)gridDim.x * 256;
        for (; i < n4; i += stride) {
            float4 v = reinterpret_cast<const float4*>(x)[i];
            ushort4 o;
            o.x = f2bf(v.x); o.y = f2bf(v.y); o.z = f2bf(v.z); o.w = f2bf(v.w);
            reinterpret_cast<ushort4*>(xb)[i] = o;
        }
    }
    // phase B: histogram
    __shared__ int h[BUCKMAX];
    for (int i = threadIdx.x; i < BUCKMAX; i += 256) h[i] = 0;
    __syncthreads();
    {
        long long i = (long long)blockIdx.x * 256 + threadIdx.x;
        const long long stride = (long long)gridDim.x * 256;
        for (; i < E; i += stride) atomicAdd(&h[rows[i] >> RPB_SHIFT], 1);
    }
    __syncthreads();
    for (int i = threadIdx.x; i < NBUCK; i += 256)
        if (h[i]) atomicAdd(&bucketCnt[i], h[i]);
}

// ---------------------------------------------------------------------------
// Fused: cast W -> bf16, then exclusive scan over NBUCK (<=256) bucket counts.
// ---------------------------------------------------------------------------
__global__ __launch_bounds__(256) void scan_castW(const float* __restrict__ W,
                                                  unsigned short* __restrict__ Wb,
                                                  const int* __restrict__ bucketCnt,
                                                  int* __restrict__ bucketBase,
                                                  int* __restrict__ bucketCur,
                                                  int* __restrict__ offsets,
                                                  int NBUCK, int N) {
    const int tid = threadIdx.x;
    for (int idx = tid; idx < D * D / 4; idx += 256) {
        float4 v = reinterpret_cast<const float4*>(W)[idx];
        ushort4 o;
        o.x = f2bf(v.x); o.y = f2bf(v.y); o.z = f2bf(v.z); o.w = f2bf(v.w);
        reinterpret_cast<ushort4*>(Wb)[idx] = o;
    }
    __shared__ int t[256];
    int v = (tid < NBUCK) ? bucketCnt[tid] : 0;
    t[tid] = v;
    __syncthreads();
    for (int ofs = 1; ofs < 256; ofs <<= 1) {
        int add = (tid >= ofs) ? t[tid - ofs] : 0;
        __syncthreads();
        t[tid] += add;
        __syncthreads();
    }
    if (tid < NBUCK) {
        bucketBase[tid] = t[tid] - v;  // exclusive
        bucketCur[tid] = 0;
    }
    if (tid == NBUCK - 1) {
        bucketBase[NBUCK] = t[tid];
        offsets[N] = t[tid];  // == E
    }
}

// ---------------------------------------------------------------------------
// Pass 1: bin edges into bucket-major PACKED pairs: (lrow9<<23 | col, val).
// Per-tile LDS histogram, ONE global atomic reservation per (tile,bucket),
// single-stream uint2 writes into the tile's private contiguous chunk.
// ---------------------------------------------------------------------------
__global__ __launch_bounds__(1024) void binA(const int* __restrict__ rows,
                                             const int* __restrict__ cols,
                                             const float* __restrict__ vals,
                                             const int* __restrict__ bucketBase,
                                             int* __restrict__ bucketCur,
                                             uint2* __restrict__ pairs_bin,
                                             int E, int NBUCK) {
    __shared__ int h[BUCKMAX];
    __shared__ int base[BUCKMAX];
    const int t0 = blockIdx.x * TILE;
    const int tend = min(t0 + TILE, E);
    for (int i = threadIdx.x; i < NBUCK; i += 1024) h[i] = 0;
    __syncthreads();
    for (int i = t0 + threadIdx.x; i < tend; i += 1024)
        atomicAdd(&h[rows[i] >> RPB_SHIFT], 1);
    __syncthreads();
    for (int i = threadIdx.x; i < NBUCK; i += 1024) {
        int c = h[i];
        base[i] = c ? bucketBase[i] + atomicAdd(&bucketCur[i], c) : 0;
        h[i] = 0;  // reuse as local cursor
    }
    __syncthreads();
    for (int i = t0 + threadIdx.x; i < tend; i += 1024) {
        int r = rows[i];
        int b = r >> RPB_SHIFT;
        int p = base[b] + atomicAdd(&h[b], 1);
        unsigned pk = ((unsigned)(r & (RPB - 1)) << 23) | (unsigned)cols[i];
        pairs_bin[p] = make_uint2(pk, __float_as_uint(vals[i]));
    }
}

// ---------------------------------------------------------------------------
// Pass 2: per 256-row half-bucket, build the sorted CSR segment in LDS and
// write it out coalesced; emit per-row global offsets. Overflow (>SEGCAP)
// falls back to direct (correct, slower) global scatter.
// ---------------------------------------------------------------------------
__global__ __launch_bounds__(256) void csr_build(const uint2* __restrict__ pairs_bin,
                                                 const int* __restrict__ bucketBase,
                                                 int* __restrict__ offsets,
                                                 uint2* __restrict__ pairs_g, int N) {
    __shared__ int hist[HALF];
    __shared__ int cur[HALF];
    __shared__ int tsum[256];
    __shared__ uint2 pr[SEGCAP];
    __shared__ int cntBelowSh;
    const int tid = threadIdx.x;
    const int buck = blockIdx.x >> 1, half = blockIdx.x & 1;
    const int lrow0 = half * HALF;
    const int grow0 = buck * RPB + lrow0;
    const int rbeg = bucketBase[buck], rend = bucketBase[buck + 1];

    hist[tid] = 0;
    if (tid == 0) cntBelowSh = 0;
    __syncthreads();

    int below = 0;
    for (int i = rbeg + tid; i < rend; i += 256) {
        int d = (int)(pairs_bin[i].x >> 23) - lrow0;
        if ((unsigned)d < (unsigned)HALF) atomicAdd(&hist[d], 1);
        else if (d < 0) ++below;
    }
    if (below) atomicAdd(&cntBelowSh, below);
    __syncthreads();

    int part = hist[tid];
    tsum[tid] = part;
    __syncthreads();
    for (int ofs = 1; ofs < 256; ofs <<= 1) {
        int add = (tid >= ofs) ? tsum[tid - ofs] : 0;
        __syncthreads();
        tsum[tid] += add;
        __syncthreads();
    }
    const int excl = tsum[tid] - part;
    const int segcnt = tsum[255];
    const int segbase = rbeg + cntBelowSh;

    cur[tid] = excl;
    const int grow = grow0 + tid;
    if (grow < N) offsets[grow] = segbase + excl;
    __syncthreads();

    if (segcnt <= SEGCAP) {
        for (int i = rbeg + tid; i < rend; i += 256) {
            uint2 e = pairs_bin[i];
            int d = (int)(e.x >> 23) - lrow0;
            if ((unsigned)d < (unsigned)HALF) {
                int p = atomicAdd(&cur[d], 1);
                pr[p] = make_uint2(e.x & 0x7FFFFFu, e.y);
            }
        }
        __syncthreads();
        for (int p = tid; p < segcnt; p += 256) pairs_g[segbase + p] = pr[p];
    } else {
        for (int i = rbeg + tid; i < rend; i += 256) {
            uint2 e = pairs_bin[i];
            int d = (int)(e.x >> 23) - lrow0;
            if ((unsigned)d < (unsigned)HALF) {
                int p = atomicAdd(&cur[d], 1);
                pairs_g[segbase + p] = make_uint2(e.x & 0x7FFFFFu, e.y);
            }
        }
    }
}

// ---------------------------------------------------------------------------
// Fused aggregation + projection. Block = 64 output rows, 4 waves.
// Phase 1: each wave gathers 16 rows (wave-per-row, 64-pair batches,
//          branch-free groups of 16 -> 16 gathers in flight), packs the
//          fp32 sums to bf16 and stores into an XOR-SWIZZLED LDS tile
//          (byte ^= (row&7)<<4 -- else ds_read_b128 A-frags are 16-way
//          bank-conflicted at D=128, Guideline 4).
// Phase 2: out = y * W^T via mfma_f32_16x16x32_bf16 from LDS (A) + global (B).
// Writes d_out exactly once; no yb round-trip, no separate GEMM dispatch.
// ---------------------------------------------------------------------------
__global__ __launch_bounds__(256) void spmm_fused(
    const unsigned short* __restrict__ xb,
    const int* __restrict__ offsets,
    const uint2* __restrict__ pairs,
    const unsigned short* __restrict__ Wb,
    float* __restrict__ out, int N) {
    __shared__ unsigned short ylds[64 * D];  // 16 KiB, swizzled
    const int wid = threadIdx.x >> 6;
    const int lane = threadIdx.x & 63;
    const int row0 = blockIdx.x * 64;

    // ---- phase 1: gather 16 rows per wave ----
    for (int rr = 0; rr < 16; ++rr) {
        const int lr = wid * 16 + rr;     // local row 0..63
        const int grow = row0 + lr;
        float ax = 0.f, ay = 0.f;
        if (grow < N) {
            const int beg = offsets[grow], end = offsets[grow + 1];
            for (int base = beg; base < end; base += 64) {
                const int rem = min(end - base, 64);  // wave-uniform
                uint2 e = make_uint2(0u, 0u);         // pads: col 0, val 0
                if (lane < rem) e = pairs[base + lane];
                int c = (int)e.x;
                float v = __uint_as_float(e.y);

                for (int j0 = 0; j0 < rem; j0 += 16) {  // j0+jj <= 63 always
                    int cj[16];
                    float vj[16];
                    unsigned u[16];
#pragma unroll
                    for (int jj = 0; jj < 16; ++jj) {
                        cj[jj] = __shfl(c, j0 + jj);
                        vj[jj] = __shfl(v, j0 + jj);
                    }
#pragma unroll
                    for (int jj = 0; jj < 16; ++jj)
                        u[jj] = *reinterpret_cast<const unsigned*>(
                            xb + (size_t)cj[jj] * D + lane * 2);
#pragma unroll
                    for (int jj = 0; jj < 16; ++jj) {
                        ax = fmaf(vj[jj], __uint_as_float(u[jj] << 16), ax);
                        ay = fmaf(vj[jj], __uint_as_float(u[jj] & 0xFFFF0000u), ay);
                    }
                }
            }
        }
        const unsigned o = (unsigned)f2bf(ax) | ((unsigned)f2bf(ay) << 16);
        const int byteoff = lr * 256 + ((lane * 4) ^ ((lr & 7) << 4));
        *reinterpret_cast<unsigned*>(reinterpret_cast<char*>(ylds) + byteoff) = o;
    }
    __syncthreads();

    // ---- phase 2: MFMA projection (layouts m89-verified) ----
    const int r = lane & 15;
    const int kg = lane >> 4;  // 0..3
    const int lr_a = wid * 16 + r;

    f32x4 acc[8] = {};
#pragma unroll
    for (int ks = 0; ks < 4; ++ks) {
        const int k0 = ks * 32 + kg * 8;
        const int abyte = lr_a * 256 + ((k0 * 2) ^ ((lr_a & 7) << 4));
        bf16x8 a = *reinterpret_cast<const bf16x8*>(
            reinterpret_cast<const char*>(ylds) + abyte);
#pragma unroll
        for (int t = 0; t < 8; ++t) {
            bf16x8 b = *reinterpret_cast<const bf16x8*>(Wb + (size_t)(t * 16 + r) * D + k0);
            acc[t] = __builtin_amdgcn_mfma_f32_16x16x32_bf16(a, b, acc[t], 0, 0, 0);
        }
    }
#pragma unroll
    for (int t = 0; t < 8; ++t) {
#pragma unroll
        for (int i = 0; i < 4; ++i) {
            const int row = row0 + wid * 16 + kg * 4 + i;
            if (row < N) out[(size_t)row * D + t * 16 + r] = acc[t][i];
        }
    }
}

// ---------------------------------------------------------------------------
// Fallback path (tiny workspace): fp32 VALU GEMM + atomic scatter
// ---------------------------------------------------------------------------
__global__ __launch_bounds__(256) void gemm64(const float* __restrict__ x,
                                              const float* __restrict__ W,
                                              float* __restrict__ h, int N) {
    __shared__ float xs[128][64];
    __shared__ float ws[128][64];
    const int tid = threadIdx.x;
    const int m0 = blockIdx.x * 64;
    const int n0 = blockIdx.y * 64;
    for (int idx = tid; idx < 2048; idx += 256) {
        int q = idx >> 6, m = idx & 63;
        int grow = m0 + m;
        float4 v = make_float4(0.f, 0.f, 0.f, 0.f);
        if (grow < N) v = *reinterpret_cast<const float4*>(x + (size_t)grow * D + q * 4);
        xs[q * 4 + 0][m] = v.x; xs[q * 4 + 1][m] = v.y;
        xs[q * 4 + 2][m] = v.z; xs[q * 4 + 3][m] = v.w;
    }
    for (int idx = tid; idx < 2048; idx += 256) {
        int q = idx >> 6, n = idx & 63;
        float4 v = *reinterpret_cast<const float4*>(W + (size_t)(n0 + n) * D + q * 4);
        ws[q * 4 + 0][n] = v.x; ws[q * 4 + 1][n] = v.y;
        ws[q * 4 + 2][n] = v.z; ws[q * 4 + 3][n] = v.w;
    }
    __syncthreads();
    const int tm = (tid & 15) * 4;
    const int tn = (tid >> 4) * 4;
    float acc[4][4] = {};
#pragma unroll 4
    for (int k = 0; k < 128; ++k) {
        float4 a4 = *reinterpret_cast<const float4*>(&xs[k][tm]);
        float4 b4 = *reinterpret_cast<const float4*>(&ws[k][tn]);
        float a[4] = {a4.x, a4.y, a4.z, a4.w};
        float b[4] = {b4.x, b4.y, b4.z, b4.w};
#pragma unroll
        for (int rr = 0; rr < 4; ++rr)
#pragma unroll
            for (int cc = 0; cc < 4; ++cc) acc[rr][cc] = fmaf(a[rr], b[cc], acc[rr][cc]);
    }
#pragma unroll
    for (int rr = 0; rr < 4; ++rr) {
        int row = m0 + tm + rr;
        if (row < N) {
            float4 o = make_float4(acc[rr][0], acc[rr][1], acc[rr][2], acc[rr][3]);
            *reinterpret_cast<float4*>(h + (size_t)row * D + n0 + tn) = o;
        }
    }
}

__global__ __launch_bounds__(256) void scatter_edges(const float* __restrict__ h,
                                                     const int* __restrict__ rows,
                                                     const int* __restrict__ cols,
                                                     const float* __restrict__ vals,
                                                     float* __restrict__ out, int E) {
    int t = blockIdx.x * 256 + threadIdx.x;
    int e = t >> 5;
    if (e >= E) return;
    int q = t & 31;
    int r = rows[e];
    int c = cols[e];
    float v = vals[e];
    float4 m = reinterpret_cast<const float4*>(h + (size_t)c * D)[q];
    float* op = out + (size_t)r * D + q * 4;
    atomicAdd(op + 0, v * m.x);
    atomicAdd(op + 1, v * m.y);
    atomicAdd(op + 2, v * m.z);
    atomicAdd(op + 3, v * m.w);
}

extern "C" void kernel_launch(void* const* d_in, const int* in_sizes, int n_in,
                              void* d_out, int out_size, void* d_ws, size_t ws_size,
                              hipStream_t stream) {
    const float* x        = (const float*)d_in[0];
    const float* W        = (const float*)d_in[1];
    const int*   adj_rows = (const int*)d_in[2];
    const int*   adj_cols = (const int*)d_in[3];
    const float* adj_vals = (const float*)d_in[4];
    float* out = (float*)d_out;

    const int N = in_sizes[0] / D;
    const int E = in_sizes[2];
    const int NBUCK = (N + RPB - 1) / RPB;
    const int NT = (E + TILE - 1) / TILE;

    // ---- workspace carve (everything in ws; d_out written once by fused) ----
    size_t off = 0;
    auto carve = [&](size_t bytes) {
        void* p = (char*)d_ws + off;
        off += (bytes + 255) & ~(size_t)255;
        return p;
    };
    unsigned short* xb = (unsigned short*)carve((size_t)N * D * 2);      // 25.6 MB
    unsigned short* Wb = (unsigned short*)carve((size_t)D * D * 2);
    int* offsets    = (int*)carve((size_t)(N + 1) * sizeof(int));
    int* bucketCnt  = (int*)carve((size_t)BUCKMAX * sizeof(int));
    int* bucketBase = (int*)carve((size_t)(BUCKMAX + 1) * sizeof(int));
    int* bucketCur  = (int*)carve((size_t)BUCKMAX * sizeof(int));
    uint2* pairs_bin = (uint2*)carve((size_t)E * sizeof(uint2));         // 12.8 MB
    uint2* pairs_g   = (uint2*)carve((size_t)E * sizeof(uint2));         // 12.8 MB
    const size_t wsNeed = off;

    const bool fits = (wsNeed <= ws_size) && (NBUCK <= BUCKMAX) && (N < (1 << 23));

    if (fits) {
        hipMemsetAsync(bucketCnt, 0, (size_t)BUCKMAX * sizeof(int), stream);
        cast_x_hist<<<2048, 256, 0, stream>>>(x, xb, (long long)N * (D / 4),
                                              adj_rows, bucketCnt, E, NBUCK);
        scan_castW<<<1, 256, 0, stream>>>(W, Wb, bucketCnt, bucketBase, bucketCur,
                                          offsets, NBUCK, N);
        binA<<<NT, 1024, 0, stream>>>(adj_rows, adj_cols, adj_vals, bucketBase,
                                      bucketCur, pairs_bin, E, NBUCK);
        csr_build<<<NBUCK * 2, 256, 0, stream>>>(pairs_bin, bucketBase,
                                                 offsets, pairs_g, N);
        spmm_fused<<<(N + 63) / 64, 256, 0, stream>>>(xb, offsets, pairs_g, Wb,
                                                      out, N);
    } else {
        float* h = (float*)d_ws;
        hipMemsetAsync(d_out, 0, (size_t)out_size * sizeof(float), stream);
        dim3 ggrid((N + 63) / 64, D / 64);
        gemm64<<<ggrid, 256, 0, stream>>>(x, W, h, N);
        const long long tt = (long long)E * 32;
        scatter_edges<<<(int)((tt + 255) / 256), 256, 0, stream>>>(
            h, adj_rows, adj_cols, adj_vals, out, E);
    }
}

// Round 9
// 165.320 us; speedup vs baseline: 1.2156x; 1.2156x over previous
//
#include <hip/hip_runtime.h>

#define D 128          // D_IN == D_OUT == 128
#define RPB 512        // rows per bucket
#define RPB_SHIFT 9
#define HALF 256       // rows handled per csr_build block
#define BUCKMAX 256
#define TILE 8192      // edges per binning tile
#define SEGCAP 7168    // LDS pair capacity per csr_build block (56 KiB)

typedef short bf16x8 __attribute__((ext_vector_type(8)));
typedef float f32x4 __attribute__((ext_vector_type(4)));

__device__ inline unsigned short f2bf(float f) {  // RNE float->bf16
    unsigned u = __float_as_uint(f);
    unsigned r = u + 0x7FFFu + ((u >> 16) & 1u);
    return (unsigned short)(r >> 16);
}

// ---------------------------------------------------------------------------
// fp32 -> bf16 cast, 4 elements/thread, grid-stride
// ---------------------------------------------------------------------------
__global__ __launch_bounds__(256) void cast_bf16(const float* __restrict__ src,
                                                 unsigned short* __restrict__ dst,
                                                 long long n4) {
    long long i = (long long)blockIdx.x * 256 + threadIdx.x;
    const long long stride = (long long)gridDim.x * 256;
    for (; i < n4; i += stride) {
        float4 v = reinterpret_cast<const float4*>(src)[i];
        ushort4 o;
        o.x = f2bf(v.x); o.y = f2bf(v.y); o.z = f2bf(v.z); o.w = f2bf(v.w);
        reinterpret_cast<ushort4*>(dst)[i] = o;
    }
}

// ---------------------------------------------------------------------------
// Pass 0: exact per-bucket edge counts (bucket = row >> RPB_SHIFT)
// ---------------------------------------------------------------------------
__global__ __launch_bounds__(1024) void bucket_hist(const int* __restrict__ rows,
                                                    int* __restrict__ bucketCnt,
                                                    int E, int NBUCK) {
    __shared__ int h[BUCKMAX];
    for (int i = threadIdx.x; i < NBUCK; i += 1024) h[i] = 0;
    __syncthreads();
    const int t0 = blockIdx.x * TILE;
    const int tend = min(t0 + TILE, E);
    for (int i = t0 + threadIdx.x; i < tend; i += 1024)
        atomicAdd(&h[rows[i] >> RPB_SHIFT], 1);
    __syncthreads();
    for (int i = threadIdx.x; i < NBUCK; i += 1024)
        if (h[i]) atomicAdd(&bucketCnt[i], h[i]);
}

// ---------------------------------------------------------------------------
// Parallel exclusive scan over NBUCK (<=256) bucket counts; zero cursors.
// ---------------------------------------------------------------------------
__global__ __launch_bounds__(256) void bucket_scan(const int* __restrict__ bucketCnt,
                                                   int* __restrict__ bucketBase,
                                                   int* __restrict__ bucketCur,
                                                   int* __restrict__ offsets,
                                                   int NBUCK, int N) {
    __shared__ int t[256];
    const int tid = threadIdx.x;
    int v = (tid < NBUCK) ? bucketCnt[tid] : 0;
    t[tid] = v;
    __syncthreads();
    for (int ofs = 1; ofs < 256; ofs <<= 1) {
        int add = (tid >= ofs) ? t[tid - ofs] : 0;
        __syncthreads();
        t[tid] += add;
        __syncthreads();
    }
    if (tid < NBUCK) {
        bucketBase[tid] = t[tid] - v;  // exclusive
        bucketCur[tid] = 0;
    }
    if (tid == NBUCK - 1) {
        bucketBase[NBUCK] = t[tid];
        offsets[N] = t[tid];  // == E
    }
}

// ---------------------------------------------------------------------------
// Pass 1: bin edges into bucket-major PACKED pairs: (lrow9<<23 | col, val).
// ---------------------------------------------------------------------------
__global__ __launch_bounds__(1024) void binA(const int* __restrict__ rows,
                                             const int* __restrict__ cols,
                                             const float* __restrict__ vals,
                                             const int* __restrict__ bucketBase,
                                             int* __restrict__ bucketCur,
                                             uint2* __restrict__ pairs_bin,
                                             int E, int NBUCK) {
    __shared__ int h[BUCKMAX];
    __shared__ int base[BUCKMAX];
    const int t0 = blockIdx.x * TILE;
    const int tend = min(t0 + TILE, E);
    for (int i = threadIdx.x; i < NBUCK; i += 1024) h[i] = 0;
    __syncthreads();
    for (int i = t0 + threadIdx.x; i < tend; i += 1024)
        atomicAdd(&h[rows[i] >> RPB_SHIFT], 1);
    __syncthreads();
    for (int i = threadIdx.x; i < NBUCK; i += 1024) {
        int c = h[i];
        base[i] = c ? bucketBase[i] + atomicAdd(&bucketCur[i], c) : 0;
        h[i] = 0;  // reuse as local cursor
    }
    __syncthreads();
    for (int i = t0 + threadIdx.x; i < tend; i += 1024) {
        int r = rows[i];
        int b = r >> RPB_SHIFT;
        int p = base[b] + atomicAdd(&h[b], 1);
        unsigned pk = ((unsigned)(r & (RPB - 1)) << 23) | (unsigned)cols[i];
        pairs_bin[p] = make_uint2(pk, __float_as_uint(vals[i]));
    }
}

// ---------------------------------------------------------------------------
// Pass 2: per 256-row half-bucket, build the sorted CSR segment in LDS and
// write it out coalesced; emit per-row global offsets.
// ---------------------------------------------------------------------------
__global__ __launch_bounds__(256) void csr_build(const uint2* __restrict__ pairs_bin,
                                                 const int* __restrict__ bucketBase,
                                                 int* __restrict__ offsets,
                                                 uint2* __restrict__ pairs_g, int N) {
    __shared__ int hist[HALF];
    __shared__ int cur[HALF];
    __shared__ int tsum[256];
    __shared__ uint2 pr[SEGCAP];
    __shared__ int cntBelowSh;
    const int tid = threadIdx.x;
    const int buck = blockIdx.x >> 1, half = blockIdx.x & 1;
    const int lrow0 = half * HALF;
    const int grow0 = buck * RPB + lrow0;
    const int rbeg = bucketBase[buck], rend = bucketBase[buck + 1];

    hist[tid] = 0;
    if (tid == 0) cntBelowSh = 0;
    __syncthreads();

    int below = 0;
    for (int i = rbeg + tid; i < rend; i += 256) {
        int d = (int)(pairs_bin[i].x >> 23) - lrow0;
        if ((unsigned)d < (unsigned)HALF) atomicAdd(&hist[d], 1);
        else if (d < 0) ++below;
    }
    if (below) atomicAdd(&cntBelowSh, below);
    __syncthreads();

    int part = hist[tid];
    tsum[tid] = part;
    __syncthreads();
    for (int ofs = 1; ofs < 256; ofs <<= 1) {
        int add = (tid >= ofs) ? tsum[tid - ofs] : 0;
        __syncthreads();
        tsum[tid] += add;
        __syncthreads();
    }
    const int excl = tsum[tid] - part;
    const int segcnt = tsum[255];
    const int segbase = rbeg + cntBelowSh;

    cur[tid] = excl;
    const int grow = grow0 + tid;
    if (grow < N) offsets[grow] = segbase + excl;
    __syncthreads();

    if (segcnt <= SEGCAP) {
        for (int i = rbeg + tid; i < rend; i += 256) {
            uint2 e = pairs_bin[i];
            int d = (int)(e.x >> 23) - lrow0;
            if ((unsigned)d < (unsigned)HALF) {
                int p = atomicAdd(&cur[d], 1);
                pr[p] = make_uint2(e.x & 0x7FFFFFu, e.y);
            }
        }
        __syncthreads();
        for (int p = tid; p < segcnt; p += 256) pairs_g[segbase + p] = pr[p];
    } else {
        for (int i = rbeg + tid; i < rend; i += 256) {
            uint2 e = pairs_bin[i];
            int d = (int)(e.x >> 23) - lrow0;
            if ((unsigned)d < (unsigned)HALF) {
                int p = atomicAdd(&cur[d], 1);
                pairs_g[segbase + p] = make_uint2(e.x & 0x7FFFFFu, e.y);
            }
        }
    }
}

// ---------------------------------------------------------------------------
// Aggregation: y[row] = sum val * xb[col]  (bf16 gather, fp32 acc, bf16 out)
// One wave per row. NEW: u64 gathers covering 2 edges per wave-load --
// lane-half 0 handles even edges, half 1 odd edges; each lane loads 8B
// (4 bf16 cols). Groups of 32 edges -> 16 independent dwordx2 loads in
// flight (2x MLP depth of R5/R7 at half the shuffles per edge).
// Final cross-half combine: one __shfl_xor(.,32) per accumulator.
// ---------------------------------------------------------------------------
__global__ __launch_bounds__(256) void csr_gather_bf16(
    const unsigned short* __restrict__ xb,
    const int* __restrict__ offsets,
    const uint2* __restrict__ pairs,
    unsigned short* __restrict__ yb, int N) {
    const int row = blockIdx.x * 4 + (threadIdx.x >> 6);
    if (row >= N) return;
    const int lane = threadIdx.x & 63;
    const int half = lane >> 5;   // which edge of each pair this lane serves
    const int cq   = lane & 31;   // column quad: bf16 cols [4cq, 4cq+4)
    const int beg = offsets[row], end = offsets[row + 1];
    float a0 = 0.f, a1 = 0.f, a2 = 0.f, a3 = 0.f;

    for (int base = beg; base < end; base += 64) {
        const int rem = min(end - base, 64);  // wave-uniform
        uint2 e = make_uint2(0u, 0u);         // pad lanes: col 0, val 0
        if (lane < rem) e = pairs[base + lane];
        int c = (int)e.x;
        float v = __uint_as_float(e.y);

        for (int j0 = 0; j0 < rem; j0 += 32) {  // 32 edges per group
            int cj[16];
            float vj[16];
            uint2 u[16];
#pragma unroll
            for (int k = 0; k < 16; ++k) {
                const int src = j0 + 2 * k + half;  // <= 63 always
                cj[k] = __shfl(c, src);
                vj[k] = __shfl(v, src);
            }
#pragma unroll
            for (int k = 0; k < 16; ++k)
                u[k] = *reinterpret_cast<const uint2*>(
                    xb + (size_t)cj[k] * D + cq * 4);
#pragma unroll
            for (int k = 0; k < 16; ++k) {
                const unsigned lo = u[k].x, hi = u[k].y;
                a0 = fmaf(vj[k], __uint_as_float(lo << 16), a0);
                a1 = fmaf(vj[k], __uint_as_float(lo & 0xFFFF0000u), a1);
                a2 = fmaf(vj[k], __uint_as_float(hi << 16), a2);
                a3 = fmaf(vj[k], __uint_as_float(hi & 0xFFFF0000u), a3);
            }
        }
    }
    // combine the two edge-halves (lane l <-> l^32 hold same columns)
    a0 += __shfl_xor(a0, 32);
    a1 += __shfl_xor(a1, 32);
    a2 += __shfl_xor(a2, 32);
    a3 += __shfl_xor(a3, 32);
    if (half == 0) {
        const unsigned o0 = (unsigned)f2bf(a0) | ((unsigned)f2bf(a1) << 16);
        const unsigned o1 = (unsigned)f2bf(a2) | ((unsigned)f2bf(a3) << 16);
        *reinterpret_cast<uint2*>(yb + (size_t)row * D + cq * 4) =
            make_uint2(o0, o1);
    }
}

// ---------------------------------------------------------------------------
// Projection: out = y * W^T via MFMA bf16 16x16x32 (layouts m89-verified).
// ---------------------------------------------------------------------------
__global__ __launch_bounds__(256) void gemm_mfma(const unsigned short* __restrict__ yb,
                                                 const unsigned short* __restrict__ Wb,
                                                 float* __restrict__ out, int N) {
    const int wid  = threadIdx.x >> 6;
    const int lane = threadIdx.x & 63;
    const int m0   = blockIdx.x * 64 + wid * 16;
    const int r    = lane & 15;
    const int kg   = lane >> 4;  // 0..3
    const int arow = m0 + r;

    f32x4 acc[8] = {};
#pragma unroll
    for (int ks = 0; ks < 4; ++ks) {
        const int k0 = ks * 32 + kg * 8;
        bf16x8 a = {};
        if (arow < N) a = *reinterpret_cast<const bf16x8*>(yb + (size_t)arow * D + k0);
#pragma unroll
        for (int t = 0; t < 8; ++t) {
            bf16x8 b = *reinterpret_cast<const bf16x8*>(Wb + (size_t)(t * 16 + r) * D + k0);
            acc[t] = __builtin_amdgcn_mfma_f32_16x16x32_bf16(a, b, acc[t], 0, 0, 0);
        }
    }
#pragma unroll
    for (int t = 0; t < 8; ++t) {
#pragma unroll
        for (int i = 0; i < 4; ++i) {
            const int row = m0 + kg * 4 + i;
            if (row < N) out[(size_t)row * D + t * 16 + r] = acc[t][i];
        }
    }
}

// ---------------------------------------------------------------------------
// Fallback path (tiny workspace): fp32 VALU GEMM + atomic scatter
// ---------------------------------------------------------------------------
__global__ __launch_bounds__(256) void gemm64(const float* __restrict__ x,
                                              const float* __restrict__ W,
                                              float* __restrict__ h, int N) {
    __shared__ float xs[128][64];
    __shared__ float ws[128][64];
    const int tid = threadIdx.x;
    const int m0 = blockIdx.x * 64;
    const int n0 = blockIdx.y * 64;
    for (int idx = tid; idx < 2048; idx += 256) {
        int q = idx >> 6, m = idx & 63;
        int grow = m0 + m;
        float4 v = make_float4(0.f, 0.f, 0.f, 0.f);
        if (grow < N) v = *reinterpret_cast<const float4*>(x + (size_t)grow * D + q * 4);
        xs[q * 4 + 0][m] = v.x; xs[q * 4 + 1][m] = v.y;
        xs[q * 4 + 2][m] = v.z; xs[q * 4 + 3][m] = v.w;
    }
    for (int idx = tid; idx < 2048; idx += 256) {
        int q = idx >> 6, n = idx & 63;
        float4 v = *reinterpret_cast<const float4*>(W + (size_t)(n0 + n) * D + q * 4);
        ws[q * 4 + 0][n] = v.x; ws[q * 4 + 1][n] = v.y;
        ws[q * 4 + 2][n] = v.z; ws[q * 4 + 3][n] = v.w;
    }
    __syncthreads();
    const int tm = (tid & 15) * 4;
    const int tn = (tid >> 4) * 4;
    float acc[4][4] = {};
#pragma unroll 4
    for (int k = 0; k < 128; ++k) {
        float4 a4 = *reinterpret_cast<const float4*>(&xs[k][tm]);
        float4 b4 = *reinterpret_cast<const float4*>(&ws[k][tn]);
        float a[4] = {a4.x, a4.y, a4.z, a4.w};
        float b[4] = {b4.x, b4.y, b4.z, b4.w};
#pragma unroll
        for (int rr = 0; rr < 4; ++rr)
#pragma unroll
            for (int cc = 0; cc < 4; ++cc) acc[rr][cc] = fmaf(a[rr], b[cc], acc[rr][cc]);
    }
#pragma unroll
    for (int rr = 0; rr < 4; ++rr) {
        int row = m0 + tm + rr;
        if (row < N) {
            float4 o = make_float4(acc[rr][0], acc[rr][1], acc[rr][2], acc[rr][3]);
            *reinterpret_cast<float4*>(h + (size_t)row * D + n0 + tn) = o;
        }
    }
}

__global__ __launch_bounds__(256) void scatter_edges(const float* __restrict__ h,
                                                     const int* __restrict__ rows,
                                                     const int* __restrict__ cols,
                                                     const float* __restrict__ vals,
                                                     float* __restrict__ out, int E) {
    int t = blockIdx.x * 256 + threadIdx.x;
    int e = t >> 5;
    if (e >= E) return;
    int q = t & 31;
    int r = rows[e];
    int c = cols[e];
    float v = vals[e];
    float4 m = reinterpret_cast<const float4*>(h + (size_t)c * D)[q];
    float* op = out + (size_t)r * D + q * 4;
    atomicAdd(op + 0, v * m.x);
    atomicAdd(op + 1, v * m.y);
    atomicAdd(op + 2, v * m.z);
    atomicAdd(op + 3, v * m.w);
}

extern "C" void kernel_launch(void* const* d_in, const int* in_sizes, int n_in,
                              void* d_out, int out_size, void* d_ws, size_t ws_size,
                              hipStream_t stream) {
    const float* x        = (const float*)d_in[0];
    const float* W        = (const float*)d_in[1];
    const int*   adj_rows = (const int*)d_in[2];
    const int*   adj_cols = (const int*)d_in[3];
    const float* adj_vals = (const float*)d_in[4];
    float* out = (float*)d_out;

    const int N = in_sizes[0] / D;
    const int E = in_sizes[2];
    const int NBUCK = (N + RPB - 1) / RPB;
    const int NT = (E + TILE - 1) / TILE;

    // ---- workspace carve (ws) ----
    size_t off = 0;
    auto carve = [&](size_t bytes) {
        void* p = (char*)d_ws + off;
        off += (bytes + 255) & ~(size_t)255;
        return p;
    };
    unsigned short* xb = (unsigned short*)carve((size_t)N * D * 2);  // 25.6 MB
    unsigned short* yb = (unsigned short*)carve((size_t)N * D * 2);  // 25.6 MB
    unsigned short* Wb = (unsigned short*)carve((size_t)D * D * 2);
    int* offsets    = (int*)carve((size_t)(N + 1) * sizeof(int));
    int* bucketCnt  = (int*)carve((size_t)BUCKMAX * sizeof(int));
    int* bucketBase = (int*)carve((size_t)(BUCKMAX + 1) * sizeof(int));
    int* bucketCur  = (int*)carve((size_t)BUCKMAX * sizeof(int));
    const size_t wsNeed = off;

    // ---- scratch carved from d_out (dead before gemm_mfma overwrites) ----
    size_t doff = 0;
    auto carveOut = [&](size_t bytes) {
        void* p = (char*)d_out + doff;
        doff += (bytes + 255) & ~(size_t)255;
        return p;
    };
    uint2* pairs_bin = (uint2*)carveOut((size_t)E * sizeof(uint2));  // 12.8 MB
    uint2* pairs_g   = (uint2*)carveOut((size_t)E * sizeof(uint2));  // 12.8 MB
    const size_t doutNeed = doff;

    const bool fits = (wsNeed <= ws_size) &&
                      (doutNeed <= (size_t)out_size * sizeof(float)) &&
                      (NBUCK <= BUCKMAX) && (N < (1 << 23));

    if (fits) {
        cast_bf16<<<2048, 256, 0, stream>>>(x, xb, (long long)N * (D / 4));
        cast_bf16<<<16, 256, 0, stream>>>(W, Wb, (long long)D * (D / 4));
        hipMemsetAsync(bucketCnt, 0, (size_t)BUCKMAX * sizeof(int), stream);
        bucket_hist<<<NT, 1024, 0, stream>>>(adj_rows, bucketCnt, E, NBUCK);
        bucket_scan<<<1, 256, 0, stream>>>(bucketCnt, bucketBase, bucketCur,
                                           offsets, NBUCK, N);
        binA<<<NT, 1024, 0, stream>>>(adj_rows, adj_cols, adj_vals, bucketBase,
                                      bucketCur, pairs_bin, E, NBUCK);
        csr_build<<<NBUCK * 2, 256, 0, stream>>>(pairs_bin, bucketBase,
                                                 offsets, pairs_g, N);
        csr_gather_bf16<<<(N + 3) / 4, 256, 0, stream>>>(xb, offsets, pairs_g, yb, N);
        gemm_mfma<<<(N + 63) / 64, 256, 0, stream>>>(yb, Wb, out, N);
    } else {
        float* h = (float*)d_ws;
        hipMemsetAsync(d_out, 0, (size_t)out_size * sizeof(float), stream);
        dim3 ggrid((N + 63) / 64, D / 64);
        gemm64<<<ggrid, 256, 0, stream>>>(x, W, h, N);
        const long long tt = (long long)E * 32;
        scatter_edges<<<(int)((tt + 255) / 256), 256, 0, stream>>>(
            h, adj_rows, adj_cols, adj_vals, out, E);
    }
}

// Round 10
// 160.336 us; speedup vs baseline: 1.2534x; 1.0311x over previous
//
#include <hip/hip_runtime.h>

#define D 128          // D_IN == D_OUT == 128
#define RPB 512        // rows per bucket
#define RPB_SHIFT 9
#define HALF 256       // rows handled per csr_build block
#define BUCKMAX 256
#define TILE 8192      // edges per binning tile
#define SEGCAP 7168    // LDS pair capacity per csr_build block (56 KiB)

typedef short bf16x8 __attribute__((ext_vector_type(8)));
typedef float f32x4 __attribute__((ext_vector_type(4)));

__device__ inline unsigned short f2bf(float f) {  // RNE float->bf16
    unsigned u = __float_as_uint(f);
    unsigned r = u + 0x7FFFu + ((u >> 16) & 1u);
    return (unsigned short)(r >> 16);
}

// ---------------------------------------------------------------------------
// fp32 -> bf16 cast, 4 elements/thread, grid-stride
// ---------------------------------------------------------------------------
__global__ __launch_bounds__(256) void cast_bf16(const float* __restrict__ src,
                                                 unsigned short* __restrict__ dst,
                                                 long long n4) {
    long long i = (long long)blockIdx.x * 256 + threadIdx.x;
    const long long stride = (long long)gridDim.x * 256;
    for (; i < n4; i += stride) {
        float4 v = reinterpret_cast<const float4*>(src)[i];
        ushort4 o;
        o.x = f2bf(v.x); o.y = f2bf(v.y); o.z = f2bf(v.z); o.w = f2bf(v.w);
        reinterpret_cast<ushort4*>(dst)[i] = o;
    }
}

// ---------------------------------------------------------------------------
// Pass 0: exact per-bucket edge counts (bucket = row >> RPB_SHIFT)
// ---------------------------------------------------------------------------
__global__ __launch_bounds__(1024) void bucket_hist(const int* __restrict__ rows,
                                                    int* __restrict__ bucketCnt,
                                                    int E, int NBUCK) {
    __shared__ int h[BUCKMAX];
    for (int i = threadIdx.x; i < NBUCK; i += 1024) h[i] = 0;
    __syncthreads();
    const int t0 = blockIdx.x * TILE;
    const int tend = min(t0 + TILE, E);
    for (int i = t0 + threadIdx.x; i < tend; i += 1024)
        atomicAdd(&h[rows[i] >> RPB_SHIFT], 1);
    __syncthreads();
    for (int i = threadIdx.x; i < NBUCK; i += 1024)
        if (h[i]) atomicAdd(&bucketCnt[i], h[i]);
}

// ---------------------------------------------------------------------------
// Parallel exclusive scan over NBUCK (<=256) bucket counts; zero cursors.
// ---------------------------------------------------------------------------
__global__ __launch_bounds__(256) void bucket_scan(const int* __restrict__ bucketCnt,
                                                   int* __restrict__ bucketBase,
                                                   int* __restrict__ bucketCur,
                                                   int* __restrict__ offsets,
                                                   int NBUCK, int N) {
    __shared__ int t[256];
    const int tid = threadIdx.x;
    int v = (tid < NBUCK) ? bucketCnt[tid] : 0;
    t[tid] = v;
    __syncthreads();
    for (int ofs = 1; ofs < 256; ofs <<= 1) {
        int add = (tid >= ofs) ? t[tid - ofs] : 0;
        __syncthreads();
        t[tid] += add;
        __syncthreads();
    }
    if (tid < NBUCK) {
        bucketBase[tid] = t[tid] - v;  // exclusive
        bucketCur[tid] = 0;
    }
    if (tid == NBUCK - 1) {
        bucketBase[NBUCK] = t[tid];
        offsets[N] = t[tid];  // == E
    }
}

// ---------------------------------------------------------------------------
// Pass 1: bin edges into bucket-major PACKED pairs: (lrow9<<23 | col, val).
// ---------------------------------------------------------------------------
__global__ __launch_bounds__(1024) void binA(const int* __restrict__ rows,
                                             const int* __restrict__ cols,
                                             const float* __restrict__ vals,
                                             const int* __restrict__ bucketBase,
                                             int* __restrict__ bucketCur,
                                             uint2* __restrict__ pairs_bin,
                                             int E, int NBUCK) {
    __shared__ int h[BUCKMAX];
    __shared__ int base[BUCKMAX];
    const int t0 = blockIdx.x * TILE;
    const int tend = min(t0 + TILE, E);
    for (int i = threadIdx.x; i < NBUCK; i += 1024) h[i] = 0;
    __syncthreads();
    for (int i = t0 + threadIdx.x; i < tend; i += 1024)
        atomicAdd(&h[rows[i] >> RPB_SHIFT], 1);
    __syncthreads();
    for (int i = threadIdx.x; i < NBUCK; i += 1024) {
        int c = h[i];
        base[i] = c ? bucketBase[i] + atomicAdd(&bucketCur[i], c) : 0;
        h[i] = 0;  // reuse as local cursor
    }
    __syncthreads();
    for (int i = t0 + threadIdx.x; i < tend; i += 1024) {
        int r = rows[i];
        int b = r >> RPB_SHIFT;
        int p = base[b] + atomicAdd(&h[b], 1);
        unsigned pk = ((unsigned)(r & (RPB - 1)) << 23) | (unsigned)cols[i];
        pairs_bin[p] = make_uint2(pk, __float_as_uint(vals[i]));
    }
}

// ---------------------------------------------------------------------------
// Pass 2: per 256-row half-bucket, build the sorted CSR segment in LDS and
// write it out coalesced; emit per-row global offsets.
// ---------------------------------------------------------------------------
__global__ __launch_bounds__(256) void csr_build(const uint2* __restrict__ pairs_bin,
                                                 const int* __restrict__ bucketBase,
                                                 int* __restrict__ offsets,
                                                 uint2* __restrict__ pairs_g, int N) {
    __shared__ int hist[HALF];
    __shared__ int cur[HALF];
    __shared__ int tsum[256];
    __shared__ uint2 pr[SEGCAP];
    __shared__ int cntBelowSh;
    const int tid = threadIdx.x;
    const int buck = blockIdx.x >> 1, half = blockIdx.x & 1;
    const int lrow0 = half * HALF;
    const int grow0 = buck * RPB + lrow0;
    const int rbeg = bucketBase[buck], rend = bucketBase[buck + 1];

    hist[tid] = 0;
    if (tid == 0) cntBelowSh = 0;
    __syncthreads();

    int below = 0;
    for (int i = rbeg + tid; i < rend; i += 256) {
        int d = (int)(pairs_bin[i].x >> 23) - lrow0;
        if ((unsigned)d < (unsigned)HALF) atomicAdd(&hist[d], 1);
        else if (d < 0) ++below;
    }
    if (below) atomicAdd(&cntBelowSh, below);
    __syncthreads();

    int part = hist[tid];
    tsum[tid] = part;
    __syncthreads();
    for (int ofs = 1; ofs < 256; ofs <<= 1) {
        int add = (tid >= ofs) ? tsum[tid - ofs] : 0;
        __syncthreads();
        tsum[tid] += add;
        __syncthreads();
    }
    const int excl = tsum[tid] - part;
    const int segcnt = tsum[255];
    const int segbase = rbeg + cntBelowSh;

    cur[tid] = excl;
    const int grow = grow0 + tid;
    if (grow < N) offsets[grow] = segbase + excl;
    __syncthreads();

    if (segcnt <= SEGCAP) {
        for (int i = rbeg + tid; i < rend; i += 256) {
            uint2 e = pairs_bin[i];
            int d = (int)(e.x >> 23) - lrow0;
            if ((unsigned)d < (unsigned)HALF) {
                int p = atomicAdd(&cur[d], 1);
                pr[p] = make_uint2(e.x & 0x7FFFFFu, e.y);
            }
        }
        __syncthreads();
        for (int p = tid; p < segcnt; p += 256) pairs_g[segbase + p] = pr[p];
    } else {
        for (int i = rbeg + tid; i < rend; i += 256) {
            uint2 e = pairs_bin[i];
            int d = (int)(e.x >> 23) - lrow0;
            if ((unsigned)d < (unsigned)HALF) {
                int p = atomicAdd(&cur[d], 1);
                pairs_g[segbase + p] = make_uint2(e.x & 0x7FFFFFu, e.y);
            }
        }
    }
}

// ---------------------------------------------------------------------------
// Aggregation: y[row] = sum val * xb[col]  (bf16 gather, fp32 acc, bf16 out)
// One wave per row. SHFL-FREE: the 64-pair batch is staged in wave-private
// LDS (coalesced load + ds_write). Inner loop processes 4 edges per step:
// lane-group g=lane>>4 serves edge j0+4i+g via a broadcast ds_read_b64
// (16 lanes same address -> conflict-free), and gathers 16B (8 bf16 cols)
// per lane via global dwordx4. 4 unrolled steps -> 16 edges / 4 wide loads
// in flight. Pad entries are zeroed -> FMAs add 0 (col 0 line stays hot).
// Final: 8 accs combined across lane-groups with uniform shfl_xor(16/32).
// ---------------------------------------------------------------------------
__global__ __launch_bounds__(256) void csr_gather_bf16(
    const unsigned short* __restrict__ xb,
    const int* __restrict__ offsets,
    const uint2* __restrict__ pairs,
    unsigned short* __restrict__ yb, int N) {
    __shared__ uint2 prl[4][64];  // 2 KiB, wave-private slices
    const int row = blockIdx.x * 4 + (threadIdx.x >> 6);
    if (row >= N) return;
    const int wave = threadIdx.x >> 6;
    const int lane = threadIdx.x & 63;
    const int g    = lane >> 4;      // edge slot within a 4-edge group
    const int c8   = lane & 15;      // which 8-col chunk of the row
    const int beg = offsets[row], end = offsets[row + 1];

    float a[8] = {};
    for (int base = beg; base < end; base += 64) {
        const int rem = min(end - base, 64);  // wave-uniform
        uint2 e = make_uint2(0u, 0u);         // pads: col 0, val 0
        if (lane < rem) e = pairs[base + lane];
        prl[wave][lane] = e;                  // wave-private: lgkmcnt only
        __builtin_amdgcn_wave_barrier();

        for (int j0 = 0; j0 < rem; j0 += 16) {  // wave-uniform trip count
            uint2 pe[4];
            uint4 u[4];
#pragma unroll
            for (int i = 0; i < 4; ++i)
                pe[i] = prl[wave][j0 + 4 * i + g];  // 16-lane broadcast read
#pragma unroll
            for (int i = 0; i < 4; ++i)
                u[i] = *reinterpret_cast<const uint4*>(
                    xb + (size_t)pe[i].x * D + c8 * 8);
#pragma unroll
            for (int i = 0; i < 4; ++i) {
                const float v = __uint_as_float(pe[i].y);
                const unsigned w0 = u[i].x, w1 = u[i].y, w2 = u[i].z, w3 = u[i].w;
                a[0] = fmaf(v, __uint_as_float(w0 << 16), a[0]);
                a[1] = fmaf(v, __uint_as_float(w0 & 0xFFFF0000u), a[1]);
                a[2] = fmaf(v, __uint_as_float(w1 << 16), a[2]);
                a[3] = fmaf(v, __uint_as_float(w1 & 0xFFFF0000u), a[3]);
                a[4] = fmaf(v, __uint_as_float(w2 << 16), a[4]);
                a[5] = fmaf(v, __uint_as_float(w2 & 0xFFFF0000u), a[5]);
                a[6] = fmaf(v, __uint_as_float(w3 << 16), a[6]);
                a[7] = fmaf(v, __uint_as_float(w3 & 0xFFFF0000u), a[7]);
            }
        }
        __builtin_amdgcn_wave_barrier();  // don't overwrite prl while in use
    }

    // combine lane-groups: lanes l, l^16, l^32, l^48 hold same columns
#pragma unroll
    for (int i = 0; i < 8; ++i) {
        a[i] += __shfl_xor(a[i], 16);
        a[i] += __shfl_xor(a[i], 32);
    }
    if (g == 0) {
        uint4 o;
        o.x = (unsigned)f2bf(a[0]) | ((unsigned)f2bf(a[1]) << 16);
        o.y = (unsigned)f2bf(a[2]) | ((unsigned)f2bf(a[3]) << 16);
        o.z = (unsigned)f2bf(a[4]) | ((unsigned)f2bf(a[5]) << 16);
        o.w = (unsigned)f2bf(a[6]) | ((unsigned)f2bf(a[7]) << 16);
        *reinterpret_cast<uint4*>(yb + (size_t)row * D + c8 * 8) = o;
    }
}

// ---------------------------------------------------------------------------
// Projection: out = y * W^T via MFMA bf16 16x16x32 (layouts m89-verified).
// ---------------------------------------------------------------------------
__global__ __launch_bounds__(256) void gemm_mfma(const unsigned short* __restrict__ yb,
                                                 const unsigned short* __restrict__ Wb,
                                                 float* __restrict__ out, int N) {
    const int wid  = threadIdx.x >> 6;
    const int lane = threadIdx.x & 63;
    const int m0   = blockIdx.x * 64 + wid * 16;
    const int r    = lane & 15;
    const int kg   = lane >> 4;  // 0..3
    const int arow = m0 + r;

    f32x4 acc[8] = {};
#pragma unroll
    for (int ks = 0; ks < 4; ++ks) {
        const int k0 = ks * 32 + kg * 8;
        bf16x8 a = {};
        if (arow < N) a = *reinterpret_cast<const bf16x8*>(yb + (size_t)arow * D + k0);
#pragma unroll
        for (int t = 0; t < 8; ++t) {
            bf16x8 b = *reinterpret_cast<const bf16x8*>(Wb + (size_t)(t * 16 + r) * D + k0);
            acc[t] = __builtin_amdgcn_mfma_f32_16x16x32_bf16(a, b, acc[t], 0, 0, 0);
        }
    }
#pragma unroll
    for (int t = 0; t < 8; ++t) {
#pragma unroll
        for (int i = 0; i < 4; ++i) {
            const int row = m0 + kg * 4 + i;
            if (row < N) out[(size_t)row * D + t * 16 + r] = acc[t][i];
        }
    }
}

// ---------------------------------------------------------------------------
// Fallback path (tiny workspace): fp32 VALU GEMM + atomic scatter
// ---------------------------------------------------------------------------
__global__ __launch_bounds__(256) void gemm64(const float* __restrict__ x,
                                              const float* __restrict__ W,
                                              float* __restrict__ h, int N) {
    __shared__ float xs[128][64];
    __shared__ float ws[128][64];
    const int tid = threadIdx.x;
    const int m0 = blockIdx.x * 64;
    const int n0 = blockIdx.y * 64;
    for (int idx = tid; idx < 2048; idx += 256) {
        int q = idx >> 6, m = idx & 63;
        int grow = m0 + m;
        float4 v = make_float4(0.f, 0.f, 0.f, 0.f);
        if (grow < N) v = *reinterpret_cast<const float4*>(x + (size_t)grow * D + q * 4);
        xs[q * 4 + 0][m] = v.x; xs[q * 4 + 1][m] = v.y;
        xs[q * 4 + 2][m] = v.z; xs[q * 4 + 3][m] = v.w;
    }
    for (int idx = tid; idx < 2048; idx += 256) {
        int q = idx >> 6, n = idx & 63;
        float4 v = *reinterpret_cast<const float4*>(W + (size_t)(n0 + n) * D + q * 4);
        ws[q * 4 + 0][n] = v.x; ws[q * 4 + 1][n] = v.y;
        ws[q * 4 + 2][n] = v.z; ws[q * 4 + 3][n] = v.w;
    }
    __syncthreads();
    const int tm = (tid & 15) * 4;
    const int tn = (tid >> 4) * 4;
    float acc[4][4] = {};
#pragma unroll 4
    for (int k = 0; k < 128; ++k) {
        float4 a4 = *reinterpret_cast<const float4*>(&xs[k][tm]);
        float4 b4 = *reinterpret_cast<const float4*>(&ws[k][tn]);
        float a[4] = {a4.x, a4.y, a4.z, a4.w};
        float b[4] = {b4.x, b4.y, b4.z, b4.w};
#pragma unroll
        for (int rr = 0; rr < 4; ++rr)
#pragma unroll
            for (int cc = 0; cc < 4; ++cc) acc[rr][cc] = fmaf(a[rr], b[cc], acc[rr][cc]);
    }
#pragma unroll
    for (int rr = 0; rr < 4; ++rr) {
        int row = m0 + tm + rr;
        if (row < N) {
            float4 o = make_float4(acc[rr][0], acc[rr][1], acc[rr][2], acc[rr][3]);
            *reinterpret_cast<float4*>(h + (size_t)row * D + n0 + tn) = o;
        }
    }
}

__global__ __launch_bounds__(256) void scatter_edges(const float* __restrict__ h,
                                                     const int* __restrict__ rows,
                                                     const int* __restrict__ cols,
                                                     const float* __restrict__ vals,
                                                     float* __restrict__ out, int E) {
    int t = blockIdx.x * 256 + threadIdx.x;
    int e = t >> 5;
    if (e >= E) return;
    int q = t & 31;
    int r = rows[e];
    int c = cols[e];
    float v = vals[e];
    float4 m = reinterpret_cast<const float4*>(h + (size_t)c * D)[q];
    float* op = out + (size_t)r * D + q * 4;
    atomicAdd(op + 0, v * m.x);
    atomicAdd(op + 1, v * m.y);
    atomicAdd(op + 2, v * m.z);
    atomicAdd(op + 3, v * m.w);
}

extern "C" void kernel_launch(void* const* d_in, const int* in_sizes, int n_in,
                              void* d_out, int out_size, void* d_ws, size_t ws_size,
                              hipStream_t stream) {
    const float* x        = (const float*)d_in[0];
    const float* W        = (const float*)d_in[1];
    const int*   adj_rows = (const int*)d_in[2];
    const int*   adj_cols = (const int*)d_in[3];
    const float* adj_vals = (const float*)d_in[4];
    float* out = (float*)d_out;

    const int N = in_sizes[0] / D;
    const int E = in_sizes[2];
    const int NBUCK = (N + RPB - 1) / RPB;
    const int NT = (E + TILE - 1) / TILE;

    // ---- workspace carve (ws) ----
    size_t off = 0;
    auto carve = [&](size_t bytes) {
        void* p = (char*)d_ws + off;
        off += (bytes + 255) & ~(size_t)255;
        return p;
    };
    unsigned short* xb = (unsigned short*)carve((size_t)N * D * 2);  // 25.6 MB
    unsigned short* yb = (unsigned short*)carve((size_t)N * D * 2);  // 25.6 MB
    unsigned short* Wb = (unsigned short*)carve((size_t)D * D * 2);
    int* offsets    = (int*)carve((size_t)(N + 1) * sizeof(int));
    int* bucketCnt  = (int*)carve((size_t)BUCKMAX * sizeof(int));
    int* bucketBase = (int*)carve((size_t)(BUCKMAX + 1) * sizeof(int));
    int* bucketCur  = (int*)carve((size_t)BUCKMAX * sizeof(int));
    const size_t wsNeed = off;

    // ---- scratch carved from d_out (dead before gemm_mfma overwrites) ----
    size_t doff = 0;
    auto carveOut = [&](size_t bytes) {
        void* p = (char*)d_out + doff;
        doff += (bytes + 255) & ~(size_t)255;
        return p;
    };
    uint2* pairs_bin = (uint2*)carveOut((size_t)E * sizeof(uint2));  // 12.8 MB
    uint2* pairs_g   = (uint2*)carveOut((size_t)E * sizeof(uint2));  // 12.8 MB
    const size_t doutNeed = doff;

    const bool fits = (wsNeed <= ws_size) &&
                      (doutNeed <= (size_t)out_size * sizeof(float)) &&
                      (NBUCK <= BUCKMAX) && (N < (1 << 23));

    if (fits) {
        cast_bf16<<<2048, 256, 0, stream>>>(x, xb, (long long)N * (D / 4));
        cast_bf16<<<16, 256, 0, stream>>>(W, Wb, (long long)D * (D / 4));
        hipMemsetAsync(bucketCnt, 0, (size_t)BUCKMAX * sizeof(int), stream);
        bucket_hist<<<NT, 1024, 0, stream>>>(adj_rows, bucketCnt, E, NBUCK);
        bucket_scan<<<1, 256, 0, stream>>>(bucketCnt, bucketBase, bucketCur,
                                           offsets, NBUCK, N);
        binA<<<NT, 1024, 0, stream>>>(adj_rows, adj_cols, adj_vals, bucketBase,
                                      bucketCur, pairs_bin, E, NBUCK);
        csr_build<<<NBUCK * 2, 256, 0, stream>>>(pairs_bin, bucketBase,
                                                 offsets, pairs_g, N);
        csr_gather_bf16<<<(N + 3) / 4, 256, 0, stream>>>(xb, offsets, pairs_g, yb, N);
        gemm_mfma<<<(N + 63) / 64, 256, 0, stream>>>(yb, Wb, out, N);
    } else {
        float* h = (float*)d_ws;
        hipMemsetAsync(d_out, 0, (size_t)out_size * sizeof(float), stream);
        dim3 ggrid((N + 63) / 64, D / 64);
        gemm64<<<ggrid, 256, 0, stream>>>(x, W, h, N);
        const long long tt = (long long)E * 32;
        scatter_edges<<<(int)((tt + 255) / 256), 256, 0, stream>>>(
            h, adj_rows, adj_cols, adj_vals, out, E);
    }
}

// Round 11
// 158.633 us; speedup vs baseline: 1.2669x; 1.0107x over previous
//
#include <hip/hip_runtime.h>

#define D 128          // D_IN == D_OUT == 128
#define RPB 512        // rows per bucket
#define RPB_SHIFT 9
#define HALF 256       // rows handled per csr_build block
#define BUCKMAX 256
#define TILE 8192      // edges per binning tile
#define SEGCAP 7168    // LDS pair capacity per csr_build block (56 KiB)

typedef short bf16x8 __attribute__((ext_vector_type(8)));
typedef float f32x4 __attribute__((ext_vector_type(4)));

__device__ inline unsigned short f2bf(float f) {  // RNE float->bf16
    unsigned u = __float_as_uint(f);
    unsigned r = u + 0x7FFFu + ((u >> 16) & 1u);
    return (unsigned short)(r >> 16);
}

// ---------------------------------------------------------------------------
// fp32 -> bf16 cast of x (grid-stride); block 0 also zeros bucketCnt
// (replaces the hipMemsetAsync dispatch).
// ---------------------------------------------------------------------------
__global__ __launch_bounds__(256) void cast_x(const float* __restrict__ src,
                                              unsigned short* __restrict__ dst,
                                              long long n4,
                                              int* __restrict__ bucketCnt) {
    if (blockIdx.x == 0) bucketCnt[threadIdx.x & (BUCKMAX - 1)] = 0;
    long long i = (long long)blockIdx.x * 256 + threadIdx.x;
    const long long stride = (long long)gridDim.x * 256;
    for (; i < n4; i += stride) {
        float4 v = reinterpret_cast<const float4*>(src)[i];
        ushort4 o;
        o.x = f2bf(v.x); o.y = f2bf(v.y); o.z = f2bf(v.z); o.w = f2bf(v.w);
        reinterpret_cast<ushort4*>(dst)[i] = o;
    }
}

// ---------------------------------------------------------------------------
// Pass 0: exact per-bucket edge counts (bucket = row >> RPB_SHIFT)
// ---------------------------------------------------------------------------
__global__ __launch_bounds__(1024) void bucket_hist(const int* __restrict__ rows,
                                                    int* __restrict__ bucketCnt,
                                                    int E, int NBUCK) {
    __shared__ int h[BUCKMAX];
    for (int i = threadIdx.x; i < NBUCK; i += 1024) h[i] = 0;
    __syncthreads();
    const int t0 = blockIdx.x * TILE;
    const int tend = min(t0 + TILE, E);
    for (int i = t0 + threadIdx.x; i < tend; i += 1024)
        atomicAdd(&h[rows[i] >> RPB_SHIFT], 1);
    __syncthreads();
    for (int i = threadIdx.x; i < NBUCK; i += 1024)
        if (h[i]) atomicAdd(&bucketCnt[i], h[i]);
}

// ---------------------------------------------------------------------------
// Block 0: exclusive scan over NBUCK (<=256) bucket counts; zero cursors.
// Block 1: cast W -> bf16 (folds the W-cast dispatch into this launch).
// ---------------------------------------------------------------------------
__global__ __launch_bounds__(256) void scan_castW(const int* __restrict__ bucketCnt,
                                                  int* __restrict__ bucketBase,
                                                  int* __restrict__ bucketCur,
                                                  int* __restrict__ offsets,
                                                  int NBUCK, int N,
                                                  const float* __restrict__ W,
                                                  unsigned short* __restrict__ Wb) {
    const int tid = threadIdx.x;
    if (blockIdx.x == 1) {  // cast W (128x128 fp32 -> bf16)
        for (int idx = tid; idx < D * D / 4; idx += 256) {
            float4 v = reinterpret_cast<const float4*>(W)[idx];
            ushort4 o;
            o.x = f2bf(v.x); o.y = f2bf(v.y); o.z = f2bf(v.z); o.w = f2bf(v.w);
            reinterpret_cast<ushort4*>(Wb)[idx] = o;
        }
        return;
    }
    __shared__ int t[256];
    int v = (tid < NBUCK) ? bucketCnt[tid] : 0;
    t[tid] = v;
    __syncthreads();
    for (int ofs = 1; ofs < 256; ofs <<= 1) {
        int add = (tid >= ofs) ? t[tid - ofs] : 0;
        __syncthreads();
        t[tid] += add;
        __syncthreads();
    }
    if (tid < NBUCK) {
        bucketBase[tid] = t[tid] - v;  // exclusive
        bucketCur[tid] = 0;
    }
    if (tid == NBUCK - 1) {
        bucketBase[NBUCK] = t[tid];
        offsets[N] = t[tid];  // == E
    }
}

// ---------------------------------------------------------------------------
// Pass 1: bin edges into bucket-major PACKED pairs: (lrow9<<23 | col, val).
// Row ids kept in registers across phases (8/thread, fully unrolled ->
// static indices, no scratch, no 6.4 MB global re-read).
// ---------------------------------------------------------------------------
__global__ __launch_bounds__(1024) void binA(const int* __restrict__ rows,
                                             const int* __restrict__ cols,
                                             const float* __restrict__ vals,
                                             const int* __restrict__ bucketBase,
                                             int* __restrict__ bucketCur,
                                             uint2* __restrict__ pairs_bin,
                                             int E, int NBUCK) {
    __shared__ int h[BUCKMAX];
    __shared__ int base[BUCKMAX];
    const int t0 = blockIdx.x * TILE;
    const int tend = min(t0 + TILE, E);
    for (int i = threadIdx.x; i < NBUCK; i += 1024) h[i] = 0;
    __syncthreads();

    int rreg[8];  // TILE/1024 == 8 edges per thread
#pragma unroll
    for (int k = 0; k < 8; ++k) {
        const int i = t0 + threadIdx.x + k * 1024;
        rreg[k] = (i < tend) ? rows[i] : -1;
        if (rreg[k] >= 0) atomicAdd(&h[rreg[k] >> RPB_SHIFT], 1);
    }
    __syncthreads();
    for (int i = threadIdx.x; i < NBUCK; i += 1024) {
        int c = h[i];
        base[i] = c ? bucketBase[i] + atomicAdd(&bucketCur[i], c) : 0;
        h[i] = 0;  // reuse as local cursor
    }
    __syncthreads();
#pragma unroll
    for (int k = 0; k < 8; ++k) {
        const int i = t0 + threadIdx.x + k * 1024;
        if (i < tend) {
            const int r = rreg[k];
            const int b = r >> RPB_SHIFT;
            const int p = base[b] + atomicAdd(&h[b], 1);
            const unsigned pk = ((unsigned)(r & (RPB - 1)) << 23) | (unsigned)cols[i];
            pairs_bin[p] = make_uint2(pk, __float_as_uint(vals[i]));
        }
    }
}

// ---------------------------------------------------------------------------
// Pass 2: per 256-row half-bucket, build the sorted CSR segment in LDS and
// write it out coalesced; emit per-row global offsets.
// ---------------------------------------------------------------------------
__global__ __launch_bounds__(256) void csr_build(const uint2* __restrict__ pairs_bin,
                                                 const int* __restrict__ bucketBase,
                                                 int* __restrict__ offsets,
                                                 uint2* __restrict__ pairs_g, int N) {
    __shared__ int hist[HALF];
    __shared__ int cur[HALF];
    __shared__ int tsum[256];
    __shared__ uint2 pr[SEGCAP];
    __shared__ int cntBelowSh;
    const int tid = threadIdx.x;
    const int buck = blockIdx.x >> 1, half = blockIdx.x & 1;
    const int lrow0 = half * HALF;
    const int grow0 = buck * RPB + lrow0;
    const int rbeg = bucketBase[buck], rend = bucketBase[buck + 1];

    hist[tid] = 0;
    if (tid == 0) cntBelowSh = 0;
    __syncthreads();

    int below = 0;
    for (int i = rbeg + tid; i < rend; i += 256) {
        int d = (int)(pairs_bin[i].x >> 23) - lrow0;
        if ((unsigned)d < (unsigned)HALF) atomicAdd(&hist[d], 1);
        else if (d < 0) ++below;
    }
    if (below) atomicAdd(&cntBelowSh, below);
    __syncthreads();

    int part = hist[tid];
    tsum[tid] = part;
    __syncthreads();
    for (int ofs = 1; ofs < 256; ofs <<= 1) {
        int add = (tid >= ofs) ? tsum[tid - ofs] : 0;
        __syncthreads();
        tsum[tid] += add;
        __syncthreads();
    }
    const int excl = tsum[tid] - part;
    const int segcnt = tsum[255];
    const int segbase = rbeg + cntBelowSh;

    cur[tid] = excl;
    const int grow = grow0 + tid;
    if (grow < N) offsets[grow] = segbase + excl;
    __syncthreads();

    if (segcnt <= SEGCAP) {
        for (int i = rbeg + tid; i < rend; i += 256) {
            uint2 e = pairs_bin[i];
            int d = (int)(e.x >> 23) - lrow0;
            if ((unsigned)d < (unsigned)HALF) {
                int p = atomicAdd(&cur[d], 1);
                pr[p] = make_uint2(e.x & 0x7FFFFFu, e.y);
            }
        }
        __syncthreads();
        for (int p = tid; p < segcnt; p += 256) pairs_g[segbase + p] = pr[p];
    } else {
        for (int i = rbeg + tid; i < rend; i += 256) {
            uint2 e = pairs_bin[i];
            int d = (int)(e.x >> 23) - lrow0;
            if ((unsigned)d < (unsigned)HALF) {
                int p = atomicAdd(&cur[d], 1);
                pairs_g[segbase + p] = make_uint2(e.x & 0x7FFFFFu, e.y);
            }
        }
    }
}

// ---------------------------------------------------------------------------
// Aggregation: y[row] = sum val * xb[col]  (bf16 gather, fp32 acc, bf16 out)
// One wave per row, shfl-free LDS-staged batches, 4x dwordx4 gathers in
// flight (R10-proven, 55.7 us).
// ---------------------------------------------------------------------------
__global__ __launch_bounds__(256) void csr_gather_bf16(
    const unsigned short* __restrict__ xb,
    const int* __restrict__ offsets,
    const uint2* __restrict__ pairs,
    unsigned short* __restrict__ yb, int N) {
    __shared__ uint2 prl[4][64];  // 2 KiB, wave-private slices
    const int row = blockIdx.x * 4 + (threadIdx.x >> 6);
    if (row >= N) return;
    const int wave = threadIdx.x >> 6;
    const int lane = threadIdx.x & 63;
    const int g    = lane >> 4;      // edge slot within a 4-edge group
    const int c8   = lane & 15;      // which 8-col chunk of the row
    const int beg = offsets[row], end = offsets[row + 1];

    float a[8] = {};
    for (int base = beg; base < end; base += 64) {
        const int rem = min(end - base, 64);  // wave-uniform
        uint2 e = make_uint2(0u, 0u);         // pads: col 0, val 0
        if (lane < rem) e = pairs[base + lane];
        prl[wave][lane] = e;                  // wave-private: lgkmcnt only
        __builtin_amdgcn_wave_barrier();

        for (int j0 = 0; j0 < rem; j0 += 16) {  // wave-uniform trip count
            uint2 pe[4];
            uint4 u[4];
#pragma unroll
            for (int i = 0; i < 4; ++i)
                pe[i] = prl[wave][j0 + 4 * i + g];  // 16-lane broadcast read
#pragma unroll
            for (int i = 0; i < 4; ++i)
                u[i] = *reinterpret_cast<const uint4*>(
                    xb + (size_t)pe[i].x * D + c8 * 8);
#pragma unroll
            for (int i = 0; i < 4; ++i) {
                const float v = __uint_as_float(pe[i].y);
                const unsigned w0 = u[i].x, w1 = u[i].y, w2 = u[i].z, w3 = u[i].w;
                a[0] = fmaf(v, __uint_as_float(w0 << 16), a[0]);
                a[1] = fmaf(v, __uint_as_float(w0 & 0xFFFF0000u), a[1]);
                a[2] = fmaf(v, __uint_as_float(w1 << 16), a[2]);
                a[3] = fmaf(v, __uint_as_float(w1 & 0xFFFF0000u), a[3]);
                a[4] = fmaf(v, __uint_as_float(w2 << 16), a[4]);
                a[5] = fmaf(v, __uint_as_float(w2 & 0xFFFF0000u), a[5]);
                a[6] = fmaf(v, __uint_as_float(w3 << 16), a[6]);
                a[7] = fmaf(v, __uint_as_float(w3 & 0xFFFF0000u), a[7]);
            }
        }
        __builtin_amdgcn_wave_barrier();  // don't overwrite prl while in use
    }

    // combine lane-groups: lanes l, l^16, l^32, l^48 hold same columns
#pragma unroll
    for (int i = 0; i < 8; ++i) {
        a[i] += __shfl_xor(a[i], 16);
        a[i] += __shfl_xor(a[i], 32);
    }
    if (g == 0) {
        uint4 o;
        o.x = (unsigned)f2bf(a[0]) | ((unsigned)f2bf(a[1]) << 16);
        o.y = (unsigned)f2bf(a[2]) | ((unsigned)f2bf(a[3]) << 16);
        o.z = (unsigned)f2bf(a[4]) | ((unsigned)f2bf(a[5]) << 16);
        o.w = (unsigned)f2bf(a[6]) | ((unsigned)f2bf(a[7]) << 16);
        *reinterpret_cast<uint4*>(yb + (size_t)row * D + c8 * 8) = o;
    }
}

// ---------------------------------------------------------------------------
// Projection: out = y * W^T via MFMA bf16 16x16x32 (layouts m89-verified).
// ---------------------------------------------------------------------------
__global__ __launch_bounds__(256) void gemm_mfma(const unsigned short* __restrict__ yb,
                                                 const unsigned short* __restrict__ Wb,
                                                 float* __restrict__ out, int N) {
    const int wid  = threadIdx.x >> 6;
    const int lane = threadIdx.x & 63;
    const int m0   = blockIdx.x * 64 + wid * 16;
    const int r    = lane & 15;
    const int kg   = lane >> 4;  // 0..3
    const int arow = m0 + r;

    f32x4 acc[8] = {};
#pragma unroll
    for (int ks = 0; ks < 4; ++ks) {
        const int k0 = ks * 32 + kg * 8;
        bf16x8 a = {};
        if (arow < N) a = *reinterpret_cast<const bf16x8*>(yb + (size_t)arow * D + k0);
#pragma unroll
        for (int t = 0; t < 8; ++t) {
            bf16x8 b = *reinterpret_cast<const bf16x8*>(Wb + (size_t)(t * 16 + r) * D + k0);
            acc[t] = __builtin_amdgcn_mfma_f32_16x16x32_bf16(a, b, acc[t], 0, 0, 0);
        }
    }
#pragma unroll
    for (int t = 0; t < 8; ++t) {
#pragma unroll
        for (int i = 0; i < 4; ++i) {
            const int row = m0 + kg * 4 + i;
            if (row < N) out[(size_t)row * D + t * 16 + r] = acc[t][i];
        }
    }
}

// ---------------------------------------------------------------------------
// Fallback path (tiny workspace): fp32 VALU GEMM + atomic scatter
// ---------------------------------------------------------------------------
__global__ __launch_bounds__(256) void gemm64(const float* __restrict__ x,
                                              const float* __restrict__ W,
                                              float* __restrict__ h, int N) {
    __shared__ float xs[128][64];
    __shared__ float ws[128][64];
    const int tid = threadIdx.x;
    const int m0 = blockIdx.x * 64;
    const int n0 = blockIdx.y * 64;
    for (int idx = tid; idx < 2048; idx += 256) {
        int q = idx >> 6, m = idx & 63;
        int grow = m0 + m;
        float4 v = make_float4(0.f, 0.f, 0.f, 0.f);
        if (grow < N) v = *reinterpret_cast<const float4*>(x + (size_t)grow * D + q * 4);
        xs[q * 4 + 0][m] = v.x; xs[q * 4 + 1][m] = v.y;
        xs[q * 4 + 2][m] = v.z; xs[q * 4 + 3][m] = v.w;
    }
    for (int idx = tid; idx < 2048; idx += 256) {
        int q = idx >> 6, n = idx & 63;
        float4 v = *reinterpret_cast<const float4*>(W + (size_t)(n0 + n) * D + q * 4);
        ws[q * 4 + 0][n] = v.x; ws[q * 4 + 1][n] = v.y;
        ws[q * 4 + 2][n] = v.z; ws[q * 4 + 3][n] = v.w;
    }
    __syncthreads();
    const int tm = (tid & 15) * 4;
    const int tn = (tid >> 4) * 4;
    float acc[4][4] = {};
#pragma unroll 4
    for (int k = 0; k < 128; ++k) {
        float4 a4 = *reinterpret_cast<const float4*>(&xs[k][tm]);
        float4 b4 = *reinterpret_cast<const float4*>(&ws[k][tn]);
        float a[4] = {a4.x, a4.y, a4.z, a4.w};
        float b[4] = {b4.x, b4.y, b4.z, b4.w};
#pragma unroll
        for (int rr = 0; rr < 4; ++rr)
#pragma unroll
            for (int cc = 0; cc < 4; ++cc) acc[rr][cc] = fmaf(a[rr], b[cc], acc[rr][cc]);
    }
#pragma unroll
    for (int rr = 0; rr < 4; ++rr) {
        int row = m0 + tm + rr;
        if (row < N) {
            float4 o = make_float4(acc[rr][0], acc[rr][1], acc[rr][2], acc[rr][3]);
            *reinterpret_cast<float4*>(h + (size_t)row * D + n0 + tn) = o;
        }
    }
}

__global__ __launch_bounds__(256) void scatter_edges(const float* __restrict__ h,
                                                     const int* __restrict__ rows,
                                                     const int* __restrict__ cols,
                                                     const float* __restrict__ vals,
                                                     float* __restrict__ out, int E) {
    int t = blockIdx.x * 256 + threadIdx.x;
    int e = t >> 5;
    if (e >= E) return;
    int q = t & 31;
    int r = rows[e];
    int c = cols[e];
    float v = vals[e];
    float4 m = reinterpret_cast<const float4*>(h + (size_t)c * D)[q];
    float* op = out + (size_t)r * D + q * 4;
    atomicAdd(op + 0, v * m.x);
    atomicAdd(op + 1, v * m.y);
    atomicAdd(op + 2, v * m.z);
    atomicAdd(op + 3, v * m.w);
}

extern "C" void kernel_launch(void* const* d_in, const int* in_sizes, int n_in,
                              void* d_out, int out_size, void* d_ws, size_t ws_size,
                              hipStream_t stream) {
    const float* x        = (const float*)d_in[0];
    const float* W        = (const float*)d_in[1];
    const int*   adj_rows = (const int*)d_in[2];
    const int*   adj_cols = (const int*)d_in[3];
    const float* adj_vals = (const float*)d_in[4];
    float* out = (float*)d_out;

    const int N = in_sizes[0] / D;
    const int E = in_sizes[2];
    const int NBUCK = (N + RPB - 1) / RPB;
    const int NT = (E + TILE - 1) / TILE;

    // ---- workspace carve (ws) ----
    size_t off = 0;
    auto carve = [&](size_t bytes) {
        void* p = (char*)d_ws + off;
        off += (bytes + 255) & ~(size_t)255;
        return p;
    };
    unsigned short* xb = (unsigned short*)carve((size_t)N * D * 2);  // 25.6 MB
    unsigned short* yb = (unsigned short*)carve((size_t)N * D * 2);  // 25.6 MB
    unsigned short* Wb = (unsigned short*)carve((size_t)D * D * 2);
    int* offsets    = (int*)carve((size_t)(N + 1) * sizeof(int));
    int* bucketCnt  = (int*)carve((size_t)BUCKMAX * sizeof(int));
    int* bucketBase = (int*)carve((size_t)(BUCKMAX + 1) * sizeof(int));
    int* bucketCur  = (int*)carve((size_t)BUCKMAX * sizeof(int));
    const size_t wsNeed = off;

    // ---- scratch carved from d_out (dead before gemm_mfma overwrites) ----
    size_t doff = 0;
    auto carveOut = [&](size_t bytes) {
        void* p = (char*)d_out + doff;
        doff += (bytes + 255) & ~(size_t)255;
        return p;
    };
    uint2* pairs_bin = (uint2*)carveOut((size_t)E * sizeof(uint2));  // 12.8 MB
    uint2* pairs_g   = (uint2*)carveOut((size_t)E * sizeof(uint2));  // 12.8 MB
    const size_t doutNeed = doff;

    const bool fits = (wsNeed <= ws_size) &&
                      (doutNeed <= (size_t)out_size * sizeof(float)) &&
                      (NBUCK <= BUCKMAX) && (N < (1 << 23));

    if (fits) {
        cast_x<<<2048, 256, 0, stream>>>(x, xb, (long long)N * (D / 4), bucketCnt);
        bucket_hist<<<NT, 1024, 0, stream>>>(adj_rows, bucketCnt, E, NBUCK);
        scan_castW<<<2, 256, 0, stream>>>(bucketCnt, bucketBase, bucketCur,
                                          offsets, NBUCK, N, W, Wb);
        binA<<<NT, 1024, 0, stream>>>(adj_rows, adj_cols, adj_vals, bucketBase,
                                      bucketCur, pairs_bin, E, NBUCK);
        csr_build<<<NBUCK * 2, 256, 0, stream>>>(pairs_bin, bucketBase,
                                                 offsets, pairs_g, N);
        csr_gather_bf16<<<(N + 3) / 4, 256, 0, stream>>>(xb, offsets, pairs_g, yb, N);
        gemm_mfma<<<(N + 63) / 64, 256, 0, stream>>>(yb, Wb, out, N);
    } else {
        float* h = (float*)d_ws;
        hipMemsetAsync(d_out, 0, (size_t)out_size * sizeof(float), stream);
        dim3 ggrid((N + 63) / 64, D / 64);
        gemm64<<<ggrid, 256, 0, stream>>>(x, W, h, N);
        const long long tt = (long long)E * 32;
        scatter_edges<<<(int)((tt + 255) / 256), 256, 0, stream>>>(
            h, adj_rows, adj_cols, adj_vals, out, E);
    }
}